// Round 1
// baseline (5725.560 us; speedup 1.0000x reference)
//
#include <hip/hip_runtime.h>
#include <hip/hip_bf16.h>
#include <math.h>

#define B_ 8
#define C_ 256
#define N_ 1024
#define H_ 8
#define DH 96                 // flattened head dim = (C/H)*3
#define BHN (C_*3*N_)         // per-batch elements of an x-like tensor = 786432

// ---------------------------------------------------------------------------
// Mask normalization: reference mask is bool[B,N]; harness dtype is ambiguous
// (int32 / fp32 / byte-bool). Detect and normalize to uint8 0/1 in ws.
// ---------------------------------------------------------------------------
__global__ void mask_norm_kernel(const unsigned* __restrict__ mraw,
                                 unsigned char* __restrict__ mout) {
  __shared__ int notI, notF;
  if (threadIdx.x == 0) { notI = 0; notF = 0; }
  __syncthreads();
  int li = 0, lf = 0;
  // first 2048 words = 8192 bytes: safe under every interpretation
  for (int i = threadIdx.x; i < 2048; i += 256) {
    unsigned w = mraw[i];
    if (w > 1u) li = 1;
    if (w != 0u && w != 0x3F800000u) lf = 1;
  }
  if (li) atomicOr(&notI, 1);
  if (lf) atomicOr(&notF, 1);
  __syncthreads();
  const int total = B_ * N_;  // 8192
  if (!notI) {               // int32 0/1
    for (int i = threadIdx.x; i < total; i += 256)
      mout[i] = (unsigned char)(mraw[i] & 1u);
  } else if (!notF) {        // float32 0.0/1.0
    for (int i = threadIdx.x; i < total; i += 256)
      mout[i] = (mraw[i] != 0u) ? 1 : 0;
  } else {                   // byte bool
    const unsigned char* m8 = (const unsigned char*)mraw;
    for (int i = threadIdx.x; i < total; i += 256)
      mout[i] = m8[i] ? 1 : 0;
  }
}

// ---------------------------------------------------------------------------
// GEMM: O[b] = W (256x256) @ X[b] (256 x 3072), fp32, 128x128 tile, 8x8/thread
// grid: (cols/128, rows/128, batches*nw); z -> (b = z/nw, w = z%nw)
// ---------------------------------------------------------------------------
#define GBM 128
#define GBN 128
#define GBK 32
#define LDA (GBM + 4)
#define LDB (GBN + 4)

__global__ __launch_bounds__(256, 2) void gemm_kernel(
    const float* __restrict__ X,
    const float* __restrict__ W0, const float* __restrict__ W1,
    const float* __restrict__ W2,
    float* __restrict__ O0, float* __restrict__ O1, float* __restrict__ O2,
    int nw) {
  const int zz = blockIdx.z;
  const int w = zz % nw;
  const int b = zz / nw;
  const float* W = (w == 0) ? W0 : (w == 1) ? W1 : W2;
  float* O = (w == 0) ? O0 : (w == 1) ? O1 : O2;
  const float* Xb = X + (size_t)b * BHN;
  float* Ob = O + (size_t)b * BHN;
  const int m0 = blockIdx.y * GBM;
  const int n0 = blockIdx.x * GBN;

  __shared__ float As[GBK][LDA];  // transposed: As[k][m]
  __shared__ float Bs[GBK][LDB];

  const int tid = threadIdx.x;
  const int tm = tid >> 4;   // 0..15 -> rows tm*8..tm*8+7
  const int tn = tid & 15;   // 0..15 -> cols tn*8..tn*8+7

  float acc[8][8];
#pragma unroll
  for (int i = 0; i < 8; ++i)
#pragma unroll
    for (int j = 0; j < 8; ++j) acc[i][j] = 0.f;

  for (int k0 = 0; k0 < C_; k0 += GBK) {
#pragma unroll
    for (int i = 0; i < (GBM * GBK) / 256; ++i) {  // 16 elems/thread
      int e = tid + i * 256;
      int m = e >> 5, kk = e & 31;
      As[kk][m] = W[(size_t)(m0 + m) * C_ + k0 + kk];
    }
#pragma unroll
    for (int i = 0; i < (GBK * GBN) / 256; ++i) {
      int e = tid + i * 256;
      int kk = e >> 7, n = e & 127;
      Bs[kk][n] = Xb[(size_t)(k0 + kk) * 3072 + n0 + n];
    }
    __syncthreads();
#pragma unroll
    for (int kk = 0; kk < GBK; ++kk) {
      float4 a0 = *(const float4*)&As[kk][tm * 8];
      float4 a1 = *(const float4*)&As[kk][tm * 8 + 4];
      float4 b0 = *(const float4*)&Bs[kk][tn * 8];
      float4 b1 = *(const float4*)&Bs[kk][tn * 8 + 4];
      float av[8] = {a0.x, a0.y, a0.z, a0.w, a1.x, a1.y, a1.z, a1.w};
      float bv[8] = {b0.x, b0.y, b0.z, b0.w, b1.x, b1.y, b1.z, b1.w};
#pragma unroll
      for (int i = 0; i < 8; ++i)
#pragma unroll
        for (int j = 0; j < 8; ++j)
          acc[i][j] = fmaf(av[i], bv[j], acc[i][j]);
    }
    __syncthreads();
  }
#pragma unroll
  for (int i = 0; i < 8; ++i) {
    int m = m0 + tm * 8 + i;
    float4* orow = (float4*)&Ob[(size_t)m * 3072 + n0 + tn * 8];
    orow[0] = make_float4(acc[i][0], acc[i][1], acc[i][2], acc[i][3]);
    orow[1] = make_float4(acc[i][4], acc[i][5], acc[i][6], acc[i][7]);
  }
}

// ---------------------------------------------------------------------------
// Flash attention, fp32. grid: (N/64, B*H). Block 256 threads.
// Per (b,h): head base = b*BHN + h*96*N; row r = i*3+dd (matches reference D
// flattening), contiguous in n.
// Thread (ty,tx), ty=tid/16, tx=tid%16: owns S rows qi=ty+16r, cols mi=tx+16j
// (strided to keep LDS reads 2-way-conflict-free), PV cols d=tx*6+dd.
// ---------------------------------------------------------------------------
#define QT 64
#define MT 64
#define LDS_D 100   // row stride (floats): 400B, 16B-aligned, odd mod 32 banks
#define LDP 65

__global__ __launch_bounds__(256, 2) void attn_kernel(
    const float* __restrict__ q, const float* __restrict__ k,
    const float* __restrict__ v, const unsigned char* __restrict__ mask,
    float* __restrict__ y) {
  const int bh = blockIdx.y;
  const int b = bh >> 3, h = bh & 7;
  const int n0 = blockIdx.x * QT;
  const float* qb = q + (size_t)b * BHN + (size_t)h * DH * N_;
  const float* kb = k + (size_t)b * BHN + (size_t)h * DH * N_;
  const float* vb = v + (size_t)b * BHN + (size_t)h * DH * N_;
  float* yb = y + (size_t)b * BHN + (size_t)h * DH * N_;
  const unsigned char* mb = mask + b * N_;

  __shared__ float Qs[QT][LDS_D];
  __shared__ float Ks[MT][LDS_D];
  __shared__ float Vs[MT][LDS_D];
  __shared__ unsigned char msk[MT];

  const int tid = threadIdx.x;
  const int ty = tid >> 4, tx = tid & 15;

  // load Q tile: Qs[n][r] = qb[r*N + n0+n]  (coalesced over n)
#pragma unroll
  for (int i = 0; i < (DH * QT) / 256; ++i) {
    int e = tid + i * 256;
    int r = e >> 6, n = e & 63;
    Qs[n][r] = qb[(size_t)r * N_ + n0 + n];
  }

  float M[4], L[4], yacc[4][6];
#pragma unroll
  for (int r = 0; r < 4; ++r) {
    M[r] = -INFINITY;
    L[r] = 0.f;
#pragma unroll
    for (int d = 0; d < 6; ++d) yacc[r][d] = 0.f;
  }

  const float sc = 0.10206207261596575f;  // 1/sqrt(96)

  for (int m0 = 0; m0 < N_; m0 += MT) {
    __syncthreads();  // prior PV done before overwriting Ks/Vs
#pragma unroll
    for (int i = 0; i < (DH * MT) / 256; ++i) {
      int e = tid + i * 256;
      int r = e >> 6, n = e & 63;
      Ks[n][r] = kb[(size_t)r * N_ + m0 + n];
      Vs[n][r] = vb[(size_t)r * N_ + m0 + n];
    }
    if (tid < MT) msk[tid] = mb[m0 + tid];
    __syncthreads();

    // ---- S = Q.K^T (16 scores/thread) ----
    float s[4][4];
#pragma unroll
    for (int r = 0; r < 4; ++r)
#pragma unroll
      for (int j = 0; j < 4; ++j) s[r][j] = 0.f;
#pragma unroll
    for (int d0 = 0; d0 < DH; d0 += 4) {
      float4 qf[4], kf[4];
#pragma unroll
      for (int r = 0; r < 4; ++r) qf[r] = *(const float4*)&Qs[ty + 16 * r][d0];
#pragma unroll
      for (int j = 0; j < 4; ++j) kf[j] = *(const float4*)&Ks[tx + 16 * j][d0];
#pragma unroll
      for (int r = 0; r < 4; ++r)
#pragma unroll
        for (int j = 0; j < 4; ++j) {
          s[r][j] = fmaf(qf[r].x, kf[j].x, s[r][j]);
          s[r][j] = fmaf(qf[r].y, kf[j].y, s[r][j]);
          s[r][j] = fmaf(qf[r].z, kf[j].z, s[r][j]);
          s[r][j] = fmaf(qf[r].w, kf[j].w, s[r][j]);
        }
    }
    // mask + scale
#pragma unroll
    for (int j = 0; j < 4; ++j) {
      bool pad = msk[tx + 16 * j] != 0;
#pragma unroll
      for (int r = 0; r < 4; ++r) s[r][j] = pad ? -INFINITY : s[r][j] * sc;
    }
    __syncthreads();  // all Ks reads done; Ps overlays Ks
    float* Ps = (float*)Ks;

    // ---- online softmax (row stats across the 16 tx lanes) ----
#pragma unroll
    for (int r = 0; r < 4; ++r) {
      float mx = fmaxf(fmaxf(s[r][0], s[r][1]), fmaxf(s[r][2], s[r][3]));
#pragma unroll
      for (int off = 8; off >= 1; off >>= 1)
        mx = fmaxf(mx, __shfl_xor(mx, off, 16));
      float newM = fmaxf(M[r], mx);
      float corr = (M[r] == newM) ? 1.f : __expf(M[r] - newM);
      float psum = 0.f;
#pragma unroll
      for (int j = 0; j < 4; ++j) {
        float p = (newM == -INFINITY) ? 0.f : __expf(s[r][j] - newM);
        s[r][j] = p;
        psum += p;
      }
#pragma unroll
      for (int off = 8; off >= 1; off >>= 1)
        psum += __shfl_xor(psum, off, 16);
      L[r] = L[r] * corr + psum;
      M[r] = newM;
#pragma unroll
      for (int d = 0; d < 6; ++d) yacc[r][d] *= corr;
#pragma unroll
      for (int j = 0; j < 4; ++j)
        Ps[(ty + 16 * r) * LDP + tx + 16 * j] = s[r][j];
    }
    __syncthreads();  // P visible

    // ---- PV accumulate ----
#pragma unroll 4
    for (int mi = 0; mi < MT; ++mi) {
      float pv[4];
#pragma unroll
      for (int r = 0; r < 4; ++r) pv[r] = Ps[(ty + 16 * r) * LDP + mi];
      float vv6[6];
#pragma unroll
      for (int d = 0; d < 6; ++d) vv6[d] = Vs[mi][tx * 6 + d];
#pragma unroll
      for (int r = 0; r < 4; ++r)
#pragma unroll
        for (int d = 0; d < 6; ++d)
          yacc[r][d] = fmaf(pv[r], vv6[d], yacc[r][d]);
    }
  }

  // normalize, stage to LDS, coalesced write-out (y layout == x layout)
  __syncthreads();
#pragma unroll
  for (int r = 0; r < 4; ++r) {
    float inv = 1.f / L[r];
#pragma unroll
    for (int d = 0; d < 6; ++d) Qs[ty + 16 * r][tx * 6 + d] = yacc[r][d] * inv;
  }
  __syncthreads();
#pragma unroll
  for (int i = 0; i < (DH * QT) / 256; ++i) {
    int e = tid + i * 256;
    int r = e >> 6, n = e & 63;
    yb[(size_t)r * N_ + n0 + n] = Qs[n][r];
  }
}

// ---------------------------------------------------------------------------
extern "C" void kernel_launch(void* const* d_in, const int* in_sizes, int n_in,
                              void* d_out, int out_size, void* d_ws,
                              size_t ws_size, hipStream_t stream) {
  const float* x = (const float*)d_in[0];
  const float* Wq = (const float*)d_in[1];
  const float* Wk = (const float*)d_in[2];
  const float* Wv = (const float*)d_in[3];
  const float* Wp = (const float*)d_in[4];
  const unsigned* mask = (const unsigned*)d_in[5];
  float* out = (float*)d_out;

  float* q = (float*)d_ws;                    // [B,C,3,N] fp32, 25.2 MB
  float* kk = q + (size_t)B_ * BHN;           // 25.2 MB
  float* vv = kk + (size_t)B_ * BHN;          // 25.2 MB
  unsigned char* mnorm = (unsigned char*)(vv + (size_t)B_ * BHN);  // 8 KB

  mask_norm_kernel<<<1, 256, 0, stream>>>(mask, mnorm);

  dim3 g1(3072 / GBN, C_ / GBM, B_ * 3);
  gemm_kernel<<<g1, 256, 0, stream>>>(x, Wq, Wk, Wv, q, kk, vv, 3);

  dim3 g2(N_ / QT, B_ * H_);
  // y aliases q: each block reads its q range into LDS before writing it.
  attn_kernel<<<g2, 256, 0, stream>>>(q, kk, vv, mnorm, q);

  dim3 g3(3072 / GBN, C_ / GBM, B_);
  gemm_kernel<<<g3, 256, 0, stream>>>(q, Wp, Wp, Wp, out, out, out, 1);
}

// Round 2
// 287.408 us; speedup vs baseline: 19.9214x; 19.9214x over previous
//
#include <hip/hip_runtime.h>
#include <hip/hip_bf16.h>
#include <math.h>

#define B_ 8
#define C_ 256
#define N_ 1024
#define H_ 8
#define DH 96                 // flattened head dim = (C/H)*3
#define BHN (C_*3*N_)         // per-batch elements of an x-like tensor = 786432

typedef _Float16 half8 __attribute__((ext_vector_type(8)));
typedef float f32x4 __attribute__((ext_vector_type(4)));

union HU { unsigned u; _Float16 h[2]; };
union HF16 { half8 v; uint2 u[2]; };

__device__ inline half8 ldpair(const _Float16* p0, const _Float16* p1) {
  HF16 f;
  f.u[0] = *(const uint2*)p0;
  f.u[1] = *(const uint2*)p1;
  return f.v;
}

// ---------------------------------------------------------------------------
// Mask normalization -> additive float mask (0 or -1e30). Input dtype is
// ambiguous (int32 / fp32 / byte-bool); detect and normalize.
// ---------------------------------------------------------------------------
__global__ void mask_norm_kernel(const unsigned* __restrict__ mraw,
                                 float* __restrict__ mout) {
  __shared__ int notI, notF;
  if (threadIdx.x == 0) { notI = 0; notF = 0; }
  __syncthreads();
  int li = 0, lf = 0;
  for (int i = threadIdx.x; i < 2048; i += 256) {  // 8KB: safe for all dtypes
    unsigned w = mraw[i];
    if (w > 1u) li = 1;
    if (w != 0u && w != 0x3F800000u) lf = 1;
  }
  if (li) atomicOr(&notI, 1);
  if (lf) atomicOr(&notF, 1);
  __syncthreads();
  const int total = B_ * N_;  // 8192
  if (!notI) {
    for (int i = threadIdx.x; i < total; i += 256)
      mout[i] = (mraw[i] & 1u) ? -1e30f : 0.f;
  } else if (!notF) {
    for (int i = threadIdx.x; i < total; i += 256)
      mout[i] = (mraw[i] != 0u) ? -1e30f : 0.f;
  } else {
    const unsigned char* m8 = (const unsigned char*)mraw;
    for (int i = threadIdx.x; i < total; i += 256)
      mout[i] = m8[i] ? -1e30f : 0.f;
  }
}

// ---------------------------------------------------------------------------
// GEMM: O[b] = W (256x256) @ X[b] (256 x 3072), fp32 compute, 128x128 tile.
// OT = _Float16 (q/k/v path) or float (Wp path).
// ---------------------------------------------------------------------------
#define GBM 128
#define GBN 128
#define GBK 32
#define LDA (GBM + 4)
#define LDB (GBN + 4)

template <typename OT>
__global__ __launch_bounds__(256, 2) void gemm_kernel(
    const float* __restrict__ X,
    const float* __restrict__ W0, const float* __restrict__ W1,
    const float* __restrict__ W2,
    OT* __restrict__ O0, OT* __restrict__ O1, OT* __restrict__ O2, int nw) {
  const int zz = blockIdx.z;
  const int w = zz % nw;
  const int b = zz / nw;
  const float* W = (w == 0) ? W0 : (w == 1) ? W1 : W2;
  OT* O = (w == 0) ? O0 : (w == 1) ? O1 : O2;
  const float* Xb = X + (size_t)b * BHN;
  OT* Ob = O + (size_t)b * BHN;
  const int m0 = blockIdx.y * GBM;
  const int n0 = blockIdx.x * GBN;

  __shared__ float As[GBK][LDA];
  __shared__ float Bs[GBK][LDB];

  const int tid = threadIdx.x;
  const int tm = tid >> 4;
  const int tn = tid & 15;

  float acc[8][8];
#pragma unroll
  for (int i = 0; i < 8; ++i)
#pragma unroll
    for (int j = 0; j < 8; ++j) acc[i][j] = 0.f;

  for (int k0 = 0; k0 < C_; k0 += GBK) {
#pragma unroll
    for (int i = 0; i < (GBM * GBK) / 256; ++i) {
      int e = tid + i * 256;
      int m = e >> 5, kk = e & 31;
      As[kk][m] = W[(size_t)(m0 + m) * C_ + k0 + kk];
    }
#pragma unroll
    for (int i = 0; i < (GBK * GBN) / 256; ++i) {
      int e = tid + i * 256;
      int kk = e >> 7, n = e & 127;
      Bs[kk][n] = Xb[(size_t)(k0 + kk) * 3072 + n0 + n];
    }
    __syncthreads();
#pragma unroll
    for (int kk = 0; kk < GBK; ++kk) {
      float4 a0 = *(const float4*)&As[kk][tm * 8];
      float4 a1 = *(const float4*)&As[kk][tm * 8 + 4];
      float4 b0 = *(const float4*)&Bs[kk][tn * 8];
      float4 b1 = *(const float4*)&Bs[kk][tn * 8 + 4];
      float av[8] = {a0.x, a0.y, a0.z, a0.w, a1.x, a1.y, a1.z, a1.w};
      float bv[8] = {b0.x, b0.y, b0.z, b0.w, b1.x, b1.y, b1.z, b1.w};
#pragma unroll
      for (int i = 0; i < 8; ++i)
#pragma unroll
        for (int j = 0; j < 8; ++j)
          acc[i][j] = fmaf(av[i], bv[j], acc[i][j]);
    }
    __syncthreads();
  }
#pragma unroll
  for (int i = 0; i < 8; ++i) {
    int m = m0 + tm * 8 + i;
    if constexpr (sizeof(OT) == 2) {
      _Float16 tmp[8];
#pragma unroll
      for (int j = 0; j < 8; ++j) tmp[j] = (_Float16)acc[i][j];
      *(uint4*)&Ob[(size_t)m * 3072 + n0 + tn * 8] = *(uint4*)tmp;
    } else {
      float4* orow = (float4*)&Ob[(size_t)m * 3072 + n0 + tn * 8];
      orow[0] = make_float4(acc[i][0], acc[i][1], acc[i][2], acc[i][3]);
      orow[1] = make_float4(acc[i][4], acc[i][5], acc[i][6], acc[i][7]);
    }
  }
}

// ---------------------------------------------------------------------------
// fp16 MFMA flash attention. grid: 512 blocks (gid = qtile*64 + head so all
// 8 q-tiles of a head share an XCD), 256 threads = 4 waves, QT=128 q-rows
// per block (32 per wave), KT=64 keys per iteration.
// Fragment k-map (assumed consistently for ALL A and B operands, so any
// hardware k-permutation cancels): k = (j>>2)*16 + (lane>>4)*4 + (j&3).
// C/D layout (HW-verified): col = lane&15, row = (lane>>4)*4 + reg.
// ---------------------------------------------------------------------------
#define QT 128
#define KT 64
#define PQ 100   // Qs/Ks fp16 row stride: 200B (16 distinct banks over rows)
#define PV2 72   // Vt/Ps fp16 row stride: 144B (8B aligned)

__global__ __launch_bounds__(256, 2) void attn_kernel(
    const _Float16* __restrict__ qh, const _Float16* __restrict__ kh,
    const _Float16* __restrict__ vh, const float* __restrict__ maddg,
    float* __restrict__ y) {
  const int gid = blockIdx.x;
  const int bh = gid & 63;          // head id -> XCD = bh % 8
  const int qt = gid >> 6;
  const int b = bh >> 3, h = bh & 7;
  const size_t hb = (size_t)b * BHN + (size_t)h * DH * N_;
  const _Float16* qb = qh + hb;
  const _Float16* kb = kh + hb;
  const _Float16* vb = vh + hb;
  float* yb = y + hb;
  const float* mb = maddg + b * N_;
  const int n0 = qt * QT;

  __shared__ _Float16 Qs[QT][PQ];   // [qrow][d]
  __shared__ _Float16 Ks[KT][PQ];   // [key][d]
  __shared__ _Float16 Vt[DH][PV2];  // [d][key]
  __shared__ _Float16 Ps[QT][PV2];  // [qrow][key]
  __shared__ float madd[KT];

  const int tid = threadIdx.x;
  const int lane = tid & 63;
  const int wave = tid >> 6;
  const int lg = lane >> 4;   // 0..3
  const int ll = lane & 15;   // 0..15
  const int wq0 = wave * 32;  // this wave's q-row base within tile

  // ---- stage Q (fp16, transposed to [qrow][d]); pair loads (uint) ----
#pragma unroll
  for (int i = 0; i < (DH * QT) / 512; ++i) {  // 24 iters, 2 elems each
    int e = tid + i * 256;
    int d = e >> 6, p = e & 63;  // d row, key-pair p
    HU u;
    u.u = *(const unsigned*)&qb[(size_t)d * N_ + n0 + 2 * p];
    Qs[2 * p][d] = u.h[0];
    Qs[2 * p + 1][d] = u.h[1];
  }
  __syncthreads();

  // ---- Q fragments to registers: qf[m][ks] ----
  half8 qf[2][3];
#pragma unroll
  for (int m = 0; m < 2; ++m)
#pragma unroll
    for (int ks = 0; ks < 3; ++ks) {
      int row = wq0 + m * 16 + ll;
      int d0 = ks * 32 + lg * 4;
      qf[m][ks] = ldpair(&Qs[row][d0], &Qs[row][d0 + 16]);
    }

  float Mst[2][4], Lst[2][4];
  f32x4 yacc[2][6];
#pragma unroll
  for (int m = 0; m < 2; ++m) {
#pragma unroll
    for (int r = 0; r < 4; ++r) { Mst[m][r] = -1e30f; Lst[m][r] = 0.f; }
#pragma unroll
    for (int dt = 0; dt < 6; ++dt) yacc[m][dt] = (f32x4){0.f, 0.f, 0.f, 0.f};
  }

  const float sc = 0.10206207261596575f;  // 1/sqrt(96)

  for (int t = 0; t < N_ / KT; ++t) {
    const int m0 = t * KT;
    __syncthreads();  // prior QK/PV reads of Ks/Vt done
    // stage K transposed -> Ks[key][d]
#pragma unroll
    for (int i = 0; i < (DH * KT) / 512; ++i) {  // 12
      int e = tid + i * 256;
      int d = e >> 5, p = e & 31;
      HU u;
      u.u = *(const unsigned*)&kb[(size_t)d * N_ + m0 + 2 * p];
      Ks[2 * p][d] = u.h[0];
      Ks[2 * p + 1][d] = u.h[1];
    }
    // stage V natural -> Vt[d][key] (contiguous b32 writes)
#pragma unroll
    for (int i = 0; i < (DH * KT) / 512; ++i) {  // 12
      int e = tid + i * 256;
      int d = e >> 5, p = e & 31;
      *(unsigned*)&Vt[d][2 * p] =
          *(const unsigned*)&vb[(size_t)d * N_ + m0 + 2 * p];
    }
    if (tid < KT) madd[tid] = mb[m0 + tid];
    __syncthreads();

    // ---- S = Q.K^T : s[m][nt], rows=q, cols=key ----
    f32x4 s[2][4];
#pragma unroll
    for (int m = 0; m < 2; ++m)
#pragma unroll
      for (int nt = 0; nt < 4; ++nt) s[m][nt] = (f32x4){0.f, 0.f, 0.f, 0.f};
#pragma unroll
    for (int ks = 0; ks < 3; ++ks) {
      half8 kf[4];
#pragma unroll
      for (int nt = 0; nt < 4; ++nt) {
        int key = nt * 16 + ll;
        int d0 = ks * 32 + lg * 4;
        kf[nt] = ldpair(&Ks[key][d0], &Ks[key][d0 + 16]);
      }
#pragma unroll
      for (int m = 0; m < 2; ++m)
#pragma unroll
        for (int nt = 0; nt < 4; ++nt)
          s[m][nt] = __builtin_amdgcn_mfma_f32_16x16x32_f16(
              qf[m][ks], kf[nt], s[m][nt], 0, 0, 0);
    }

    // ---- online softmax (row stats across the 16 ll-lanes) ----
#pragma unroll
    for (int m = 0; m < 2; ++m) {
      float mad[4];
#pragma unroll
      for (int nt = 0; nt < 4; ++nt) mad[nt] = madd[nt * 16 + ll];
#pragma unroll
      for (int r = 0; r < 4; ++r) {
        float sv0 = s[m][0][r] * sc + mad[0];
        float sv1 = s[m][1][r] * sc + mad[1];
        float sv2 = s[m][2][r] * sc + mad[2];
        float sv3 = s[m][3][r] * sc + mad[3];
        float mx = fmaxf(fmaxf(sv0, sv1), fmaxf(sv2, sv3));
        mx = fmaxf(mx, __shfl_xor(mx, 1));
        mx = fmaxf(mx, __shfl_xor(mx, 2));
        mx = fmaxf(mx, __shfl_xor(mx, 4));
        mx = fmaxf(mx, __shfl_xor(mx, 8));
        float Mo = Mst[m][r];
        float newM = fmaxf(Mo, mx);
        float corr = __expf(Mo - newM);
        float p0 = __expf(sv0 - newM);
        float p1 = __expf(sv1 - newM);
        float p2 = __expf(sv2 - newM);
        float p3 = __expf(sv3 - newM);
        int row = wq0 + m * 16 + lg * 4 + r;
        Ps[row][ll] = (_Float16)p0;
        Ps[row][16 + ll] = (_Float16)p1;
        Ps[row][32 + ll] = (_Float16)p2;
        Ps[row][48 + ll] = (_Float16)p3;
        float ps = (p0 + p1) + (p2 + p3);
        ps += __shfl_xor(ps, 1);
        ps += __shfl_xor(ps, 2);
        ps += __shfl_xor(ps, 4);
        ps += __shfl_xor(ps, 8);
        Lst[m][r] = Lst[m][r] * corr + ps;
        Mst[m][r] = newM;
#pragma unroll
        for (int dt = 0; dt < 6; ++dt) yacc[m][dt][r] *= corr;
      }
    }
    // Ps writes/reads are wave-local (own 32 rows): DS pipe is in-order per
    // wave -> no barrier needed before PV.

    // ---- y += P.V ----
#pragma unroll
    for (int ks2 = 0; ks2 < 2; ++ks2) {
      half8 pf[2];
#pragma unroll
      for (int m = 0; m < 2; ++m) {
        int row = wq0 + m * 16 + ll;
        int k0 = ks2 * 32 + lg * 4;
        pf[m] = ldpair(&Ps[row][k0], &Ps[row][k0 + 16]);
      }
#pragma unroll
      for (int dt = 0; dt < 6; ++dt) {
        int d = dt * 16 + ll;
        int k0 = ks2 * 32 + lg * 4;
        half8 vf = ldpair(&Vt[d][k0], &Vt[d][k0 + 16]);
#pragma unroll
        for (int m = 0; m < 2; ++m)
          yacc[m][dt] = __builtin_amdgcn_mfma_f32_16x16x32_f16(
              pf[m], vf, yacc[m][dt], 0, 0, 0);
      }
    }
  }

  // ---- epilogue: y[d][n] fp32, float4 per (m,dt); lanes of one ll cover a
  // full 64B line along n ----
#pragma unroll
  for (int m = 0; m < 2; ++m) {
    float inv[4];
#pragma unroll
    for (int r = 0; r < 4; ++r) inv[r] = 1.f / Lst[m][r];
#pragma unroll
    for (int dt = 0; dt < 6; ++dt) {
      int d = dt * 16 + ll;
      int n = n0 + wq0 + m * 16 + lg * 4;
      float4 o;
      o.x = yacc[m][dt][0] * inv[0];
      o.y = yacc[m][dt][1] * inv[1];
      o.z = yacc[m][dt][2] * inv[2];
      o.w = yacc[m][dt][3] * inv[3];
      *(float4*)&yb[(size_t)d * N_ + n] = o;
    }
  }
}

// ---------------------------------------------------------------------------
extern "C" void kernel_launch(void* const* d_in, const int* in_sizes, int n_in,
                              void* d_out, int out_size, void* d_ws,
                              size_t ws_size, hipStream_t stream) {
  const float* x = (const float*)d_in[0];
  const float* Wq = (const float*)d_in[1];
  const float* Wk = (const float*)d_in[2];
  const float* Wv = (const float*)d_in[3];
  const float* Wp = (const float*)d_in[4];
  const unsigned* mask = (const unsigned*)d_in[5];
  float* out = (float*)d_out;

  _Float16* qh = (_Float16*)d_ws;                        // 12.6 MB
  _Float16* kh = qh + (size_t)B_ * BHN;                  // 12.6 MB
  _Float16* vh = kh + (size_t)B_ * BHN;                  // 12.6 MB
  float* yf = (float*)(vh + (size_t)B_ * BHN);           // 25.2 MB
  float* maddf = yf + (size_t)B_ * BHN;                  // 32 KB

  mask_norm_kernel<<<1, 256, 0, stream>>>(mask, maddf);

  dim3 g1(3072 / GBN, C_ / GBM, B_ * 3);
  gemm_kernel<_Float16><<<g1, 256, 0, stream>>>(x, Wq, Wk, Wv, qh, kh, vh, 3);

  attn_kernel<<<dim3(512), 256, 0, stream>>>(qh, kh, vh, maddf, yf);

  dim3 g3(3072 / GBN, C_ / GBM, B_);
  gemm_kernel<float><<<g3, 256, 0, stream>>>(yf, Wp, Wp, Wp, out, out, out, 1);
}

// Round 3
// 141.221 us; speedup vs baseline: 40.5432x; 2.0352x over previous
//
#include <hip/hip_runtime.h>
#include <hip/hip_bf16.h>
#include <math.h>

#define B_ 8
#define C_ 256
#define N_ 1024
#define H_ 8
#define DH 96                 // flattened head dim = (C/H)*3
#define BHN (C_*3*N_)         // per-batch elements of an x-like tensor = 786432

typedef _Float16 half8 __attribute__((ext_vector_type(8)));
typedef float f32x4 __attribute__((ext_vector_type(4)));

union HU { unsigned u; _Float16 h[2]; };
union HF16 { half8 v; uint2 u[2]; };

__device__ inline half8 ldpair(const _Float16* p0, const _Float16* p1) {
  HF16 f;
  f.u[0] = *(const uint2*)p0;
  f.u[1] = *(const uint2*)p1;
  return f.v;
}

typedef __attribute__((address_space(1))) void gvoid;
typedef __attribute__((address_space(3))) void lvoid;
__device__ inline void gl_lds16(const _Float16* g, _Float16* l) {
  __builtin_amdgcn_global_load_lds((gvoid*)g, (lvoid*)l, 16, 0, 0);
}

// ---------------------------------------------------------------------------
// Mask normalization -> additive float mask (0 or -1e30).
// ---------------------------------------------------------------------------
__global__ void mask_norm_kernel(const unsigned* __restrict__ mraw,
                                 float* __restrict__ mout) {
  __shared__ int notI, notF;
  if (threadIdx.x == 0) { notI = 0; notF = 0; }
  __syncthreads();
  int li = 0, lf = 0;
  for (int i = threadIdx.x; i < 2048; i += 256) {  // 8KB: safe for all dtypes
    unsigned w = mraw[i];
    if (w > 1u) li = 1;
    if (w != 0u && w != 0x3F800000u) lf = 1;
  }
  if (li) atomicOr(&notI, 1);
  if (lf) atomicOr(&notF, 1);
  __syncthreads();
  const int total = B_ * N_;
  if (!notI) {
    for (int i = threadIdx.x; i < total; i += 256)
      mout[i] = (mraw[i] & 1u) ? -1e30f : 0.f;
  } else if (!notF) {
    for (int i = threadIdx.x; i < total; i += 256)
      mout[i] = (mraw[i] != 0u) ? -1e30f : 0.f;
  } else {
    const unsigned char* m8 = (const unsigned char*)mraw;
    for (int i = threadIdx.x; i < total; i += 256)
      mout[i] = m8[i] ? -1e30f : 0.f;
  }
}

// ---------------------------------------------------------------------------
// Convert 4 weight matrices fp32 -> fp16, concatenated [4][256][256].
// ---------------------------------------------------------------------------
__global__ void convw_kernel(const float* __restrict__ Wq,
                             const float* __restrict__ Wk,
                             const float* __restrict__ Wv,
                             const float* __restrict__ Wp,
                             _Float16* __restrict__ Wh) {
  int idx = blockIdx.x * 256 + threadIdx.x;  // 32768 threads, 8 elems each
  int e0 = idx * 8;
  const float* src = (e0 < 65536) ? Wq
                   : (e0 < 131072) ? Wk
                   : (e0 < 196608) ? Wv : Wp;
  int off = e0 & 65535;
  float4 a = *(const float4*)&src[off];
  float4 b = *(const float4*)&src[off + 4];
  _Float16 t[8] = {(_Float16)a.x, (_Float16)a.y, (_Float16)a.z, (_Float16)a.w,
                   (_Float16)b.x, (_Float16)b.y, (_Float16)b.z, (_Float16)b.w};
  *(uint4*)&Wh[e0] = *(uint4*)t;
}

// ---------------------------------------------------------------------------
// Transpose-convert x: [b][C=256][3N=3072] fp32 -> XT [b][3072][256] fp16.
// 64x64 tiles via LDS.
// ---------------------------------------------------------------------------
__global__ __launch_bounds__(256) void convxt_kernel(
    const float* __restrict__ x, _Float16* __restrict__ XT) {
  __shared__ _Float16 T[64][65];
  const int m0 = blockIdx.x * 64;         // 48 tiles along 3N
  const int c0 = blockIdx.y * 64;         // 4 tiles along C
  const int b = blockIdx.z;
  const float* xb = x + (size_t)b * BHN;
  _Float16* ob = XT + (size_t)b * BHN;
  const int t = threadIdx.x;
#pragma unroll
  for (int i = 0; i < 16; ++i) {
    int e = t + i * 256;                  // 0..4095
    int c = e >> 6, m = e & 63;
    T[m][c] = (_Float16)xb[(size_t)(c0 + c) * 3072 + m0 + m];
  }
  __syncthreads();
#pragma unroll
  for (int i = 0; i < 2; ++i) {
    int e = t + i * 256;                  // 0..511
    int m = e >> 3, ch = e & 7;
    _Float16 tmp[8];
#pragma unroll
    for (int j = 0; j < 8; ++j) tmp[j] = T[m][ch * 8 + j];
    *(uint4*)&ob[(size_t)(m0 + m) * 256 + c0 + ch * 8] = *(uint4*)tmp;
  }
}

// ---------------------------------------------------------------------------
// fp16 MFMA GEMM: O[b] = W(256x256) @ X[b](256x3072).
// A = Wh[woff+w] rows [o][c]; B = Xn[b] rows [n][c] (pre-transposed).
// 128x128 tile, BK=32, 4 waves (2x2), wave tile 64x64, 16x16x32 frags.
// k-contiguous fragment order (same permutation for A and B => correct).
// LDS tiles unpadded [row][32] fp16 -> linear dest for global_load_lds.
// ---------------------------------------------------------------------------
template <typename OT>
__global__ __launch_bounds__(256, 4) void mgemm_kernel(
    const _Float16* __restrict__ Wh, int woff,
    const _Float16* __restrict__ Xn,
    OT* __restrict__ O0, OT* __restrict__ O1, OT* __restrict__ O2, int nw) {
  const int zz = blockIdx.z;
  const int w = zz % nw;
  const int b = zz / nw;
  const _Float16* Wb = Wh + (size_t)(woff + w) * 65536;
  const _Float16* Bb = Xn + (size_t)b * BHN;
  OT* Ob = ((w == 0) ? O0 : (w == 1) ? O1 : O2) + (size_t)b * BHN;
  const int o0 = blockIdx.y * 128;
  const int bn0 = blockIdx.x * 128;

  __shared__ __align__(16) _Float16 Ah[4096];  // [128][32]
  __shared__ __align__(16) _Float16 Bh[4096];  // [128][32]

  const int tid = threadIdx.x;
  const int wave = tid >> 6;
  const int lane = tid & 63;
  const int lg = lane >> 4, ll = lane & 15;
  const int wm = wave >> 1, wn = wave & 1;
  const int r0 = tid >> 2, c4 = tid & 3;  // staging chunk: row r0, 16B chunk c4

  f32x4 acc[4][4];
#pragma unroll
  for (int mi = 0; mi < 4; ++mi)
#pragma unroll
    for (int ni = 0; ni < 4; ++ni) acc[mi][ni] = (f32x4){0.f, 0.f, 0.f, 0.f};

  for (int k0 = 0; k0 < 256; k0 += 32) {
    gl_lds16(Wb + (size_t)(o0 + r0) * 256 + k0 + c4 * 8, &Ah[wave * 512]);
    gl_lds16(Wb + (size_t)(o0 + 64 + r0) * 256 + k0 + c4 * 8,
             &Ah[2048 + wave * 512]);
    gl_lds16(Bb + (size_t)(bn0 + r0) * 256 + k0 + c4 * 8, &Bh[wave * 512]);
    gl_lds16(Bb + (size_t)(bn0 + 64 + r0) * 256 + k0 + c4 * 8,
             &Bh[2048 + wave * 512]);
    __syncthreads();
    half8 af[4], bf[4];
#pragma unroll
    for (int mi = 0; mi < 4; ++mi)
      af[mi] = *(const half8*)&Ah[(wm * 64 + mi * 16 + ll) * 32 + lg * 8];
#pragma unroll
    for (int ni = 0; ni < 4; ++ni)
      bf[ni] = *(const half8*)&Bh[(wn * 64 + ni * 16 + ll) * 32 + lg * 8];
#pragma unroll
    for (int mi = 0; mi < 4; ++mi)
#pragma unroll
      for (int ni = 0; ni < 4; ++ni)
        acc[mi][ni] = __builtin_amdgcn_mfma_f32_16x16x32_f16(
            af[mi], bf[ni], acc[mi][ni], 0, 0, 0);
    __syncthreads();
  }

#pragma unroll
  for (int mi = 0; mi < 4; ++mi) {
#pragma unroll
    for (int ni = 0; ni < 4; ++ni) {
      int o = o0 + wm * 64 + mi * 16 + lg * 4;
      int n = bn0 + wn * 64 + ni * 16 + ll;
#pragma unroll
      for (int r = 0; r < 4; ++r)
        Ob[(size_t)(o + r) * 3072 + n] = (OT)acc[mi][ni][r];
    }
  }
}

// ---------------------------------------------------------------------------
// fp16 MFMA flash attention (unchanged core; epilogue now writes y^T fp16
// [b][3N][C] for the Wp GEMM, staged through LDS for coalescing).
// ---------------------------------------------------------------------------
#define QT 128
#define KT 64
#define PQ 100
#define PV2 72

__global__ __launch_bounds__(256, 2) void attn_kernel(
    const _Float16* __restrict__ qh, const _Float16* __restrict__ kh,
    const _Float16* __restrict__ vh, const float* __restrict__ maddg,
    _Float16* __restrict__ yT) {
  const int gid = blockIdx.x;
  const int bh = gid & 63;          // head id -> XCD = bh % 8
  const int qt = gid >> 6;
  const int b = bh >> 3, h = bh & 7;
  const size_t hb = (size_t)b * BHN + (size_t)h * DH * N_;
  const _Float16* qb = qh + hb;
  const _Float16* kb = kh + hb;
  const _Float16* vb = vh + hb;
  const float* mb = maddg + b * N_;
  const int n0 = qt * QT;

  __shared__ __align__(16) _Float16 Qs[QT][PQ];   // [qrow][d]; reused as Ys
  __shared__ __align__(16) _Float16 Ks[KT][PQ];   // [key][d]
  __shared__ __align__(16) _Float16 Vt[DH][PV2];  // [d][key]
  __shared__ __align__(16) _Float16 Ps[QT][PV2];  // [qrow][key]
  __shared__ float madd[KT];

  const int tid = threadIdx.x;
  const int lane = tid & 63;
  const int wave = tid >> 6;
  const int lg = lane >> 4;
  const int ll = lane & 15;
  const int wq0 = wave * 32;

#pragma unroll
  for (int i = 0; i < (DH * QT) / 512; ++i) {
    int e = tid + i * 256;
    int d = e >> 6, p = e & 63;
    HU u;
    u.u = *(const unsigned*)&qb[(size_t)d * N_ + n0 + 2 * p];
    Qs[2 * p][d] = u.h[0];
    Qs[2 * p + 1][d] = u.h[1];
  }
  __syncthreads();

  half8 qf[2][3];
#pragma unroll
  for (int m = 0; m < 2; ++m)
#pragma unroll
    for (int ks = 0; ks < 3; ++ks) {
      int row = wq0 + m * 16 + ll;
      int d0 = ks * 32 + lg * 4;
      qf[m][ks] = ldpair(&Qs[row][d0], &Qs[row][d0 + 16]);
    }

  float Mst[2][4], Lst[2][4];
  f32x4 yacc[2][6];
#pragma unroll
  for (int m = 0; m < 2; ++m) {
#pragma unroll
    for (int r = 0; r < 4; ++r) { Mst[m][r] = -1e30f; Lst[m][r] = 0.f; }
#pragma unroll
    for (int dt = 0; dt < 6; ++dt) yacc[m][dt] = (f32x4){0.f, 0.f, 0.f, 0.f};
  }

  const float sc = 0.10206207261596575f;  // 1/sqrt(96)

  for (int t = 0; t < N_ / KT; ++t) {
    const int m0 = t * KT;
    __syncthreads();
#pragma unroll
    for (int i = 0; i < (DH * KT) / 512; ++i) {
      int e = tid + i * 256;
      int d = e >> 5, p = e & 31;
      HU u;
      u.u = *(const unsigned*)&kb[(size_t)d * N_ + m0 + 2 * p];
      Ks[2 * p][d] = u.h[0];
      Ks[2 * p + 1][d] = u.h[1];
    }
#pragma unroll
    for (int i = 0; i < (DH * KT) / 512; ++i) {
      int e = tid + i * 256;
      int d = e >> 5, p = e & 31;
      *(unsigned*)&Vt[d][2 * p] =
          *(const unsigned*)&vb[(size_t)d * N_ + m0 + 2 * p];
    }
    if (tid < KT) madd[tid] = mb[m0 + tid];
    __syncthreads();

    f32x4 s[2][4];
#pragma unroll
    for (int m = 0; m < 2; ++m)
#pragma unroll
      for (int nt = 0; nt < 4; ++nt) s[m][nt] = (f32x4){0.f, 0.f, 0.f, 0.f};
#pragma unroll
    for (int ks = 0; ks < 3; ++ks) {
      half8 kf[4];
#pragma unroll
      for (int nt = 0; nt < 4; ++nt) {
        int key = nt * 16 + ll;
        int d0 = ks * 32 + lg * 4;
        kf[nt] = ldpair(&Ks[key][d0], &Ks[key][d0 + 16]);
      }
#pragma unroll
      for (int m = 0; m < 2; ++m)
#pragma unroll
        for (int nt = 0; nt < 4; ++nt)
          s[m][nt] = __builtin_amdgcn_mfma_f32_16x16x32_f16(
              qf[m][ks], kf[nt], s[m][nt], 0, 0, 0);
    }

#pragma unroll
    for (int m = 0; m < 2; ++m) {
      float mad[4];
#pragma unroll
      for (int nt = 0; nt < 4; ++nt) mad[nt] = madd[nt * 16 + ll];
#pragma unroll
      for (int r = 0; r < 4; ++r) {
        float sv0 = s[m][0][r] * sc + mad[0];
        float sv1 = s[m][1][r] * sc + mad[1];
        float sv2 = s[m][2][r] * sc + mad[2];
        float sv3 = s[m][3][r] * sc + mad[3];
        float mx = fmaxf(fmaxf(sv0, sv1), fmaxf(sv2, sv3));
        mx = fmaxf(mx, __shfl_xor(mx, 1));
        mx = fmaxf(mx, __shfl_xor(mx, 2));
        mx = fmaxf(mx, __shfl_xor(mx, 4));
        mx = fmaxf(mx, __shfl_xor(mx, 8));
        float Mo = Mst[m][r];
        float newM = fmaxf(Mo, mx);
        float corr = __expf(Mo - newM);
        float p0 = __expf(sv0 - newM);
        float p1 = __expf(sv1 - newM);
        float p2 = __expf(sv2 - newM);
        float p3 = __expf(sv3 - newM);
        int row = wq0 + m * 16 + lg * 4 + r;
        Ps[row][ll] = (_Float16)p0;
        Ps[row][16 + ll] = (_Float16)p1;
        Ps[row][32 + ll] = (_Float16)p2;
        Ps[row][48 + ll] = (_Float16)p3;
        float ps = (p0 + p1) + (p2 + p3);
        ps += __shfl_xor(ps, 1);
        ps += __shfl_xor(ps, 2);
        ps += __shfl_xor(ps, 4);
        ps += __shfl_xor(ps, 8);
        Lst[m][r] = Lst[m][r] * corr + ps;
        Mst[m][r] = newM;
#pragma unroll
        for (int dt = 0; dt < 6; ++dt) yacc[m][dt][r] *= corr;
      }
    }

#pragma unroll
    for (int ks2 = 0; ks2 < 2; ++ks2) {
      half8 pf[2];
#pragma unroll
      for (int m = 0; m < 2; ++m) {
        int row = wq0 + m * 16 + ll;
        int k0 = ks2 * 32 + lg * 4;
        pf[m] = ldpair(&Ps[row][k0], &Ps[row][k0 + 16]);
      }
#pragma unroll
      for (int dt = 0; dt < 6; ++dt) {
        int d = dt * 16 + ll;
        int k0 = ks2 * 32 + lg * 4;
        half8 vf = ldpair(&Vt[d][k0], &Vt[d][k0 + 16]);
#pragma unroll
        for (int m = 0; m < 2; ++m)
          yacc[m][dt] = __builtin_amdgcn_mfma_f32_16x16x32_f16(
              pf[m], vf, yacc[m][dt], 0, 0, 0);
      }
    }
  }

  // ---- epilogue: stage y^T tile [3][128 n][32 i] fp16 in Qs, then write
  // coalesced to yT[b][3N][C] at column block h*32. ----
  _Float16* Ys = &Qs[0][0];  // 12288 fp16 <= 12800 available
#pragma unroll
  for (int m = 0; m < 2; ++m) {
    float inv[4];
#pragma unroll
    for (int r = 0; r < 4; ++r) inv[r] = 1.f / Lst[m][r];
#pragma unroll
    for (int dt = 0; dt < 6; ++dt) {
      int d = dt * 16 + ll;
      int ii = d / 3, dd = d - ii * 3;
      int nl = wq0 + m * 16 + lg * 4;
#pragma unroll
      for (int r = 0; r < 4; ++r)
        Ys[dd * 4096 + (nl + r) * 32 + ii] = (_Float16)(yacc[m][dt][r] * inv[r]);
    }
  }
  __syncthreads();
  _Float16* yTb = yT + (size_t)b * BHN + h * 32;
#pragma unroll
  for (int i = 0; i < 6; ++i) {
    int e = tid + i * 256;                 // 0..1535
    int dd = e >> 9, rem = e & 511;
    int n = rem >> 2, ch = rem & 3;
    uint4 val = *(const uint4*)&Ys[dd * 4096 + n * 32 + ch * 8];
    *(uint4*)&yTb[(size_t)(dd * 1024 + n0 + n) * 256 + ch * 8] = val;
  }
}

// ---------------------------------------------------------------------------
extern "C" void kernel_launch(void* const* d_in, const int* in_sizes, int n_in,
                              void* d_out, int out_size, void* d_ws,
                              size_t ws_size, hipStream_t stream) {
  const float* x = (const float*)d_in[0];
  const float* Wq = (const float*)d_in[1];
  const float* Wk = (const float*)d_in[2];
  const float* Wv = (const float*)d_in[3];
  const float* Wp = (const float*)d_in[4];
  const unsigned* mask = (const unsigned*)d_in[5];
  float* out = (float*)d_out;

  _Float16* Wh = (_Float16*)d_ws;                       // 0.5 MB [4][256][256]
  _Float16* XT = Wh + 4 * 65536;                        // 12.6 MB [b][3N][C]
  _Float16* qh = XT + (size_t)B_ * BHN;                 // 12.6 MB [b][C][3N]
  _Float16* kh = qh + (size_t)B_ * BHN;
  _Float16* vh = kh + (size_t)B_ * BHN;
  _Float16* yT = vh + (size_t)B_ * BHN;                 // 12.6 MB [b][3N][C]
  float* maddf = (float*)(yT + (size_t)B_ * BHN);       // 32 KB

  mask_norm_kernel<<<1, 256, 0, stream>>>(mask, maddf);
  convw_kernel<<<128, 256, 0, stream>>>(Wq, Wk, Wv, Wp, Wh);
  convxt_kernel<<<dim3(48, 4, B_), 256, 0, stream>>>(x, XT);

  dim3 g1(24, 2, B_ * 3);
  mgemm_kernel<_Float16><<<g1, 256, 0, stream>>>(Wh, 0, XT, qh, kh, vh, 3);

  attn_kernel<<<dim3(512), 256, 0, stream>>>(qh, kh, vh, maddf, yT);

  dim3 g3(24, 2, B_);
  mgemm_kernel<float><<<g3, 256, 0, stream>>>(Wh, 3, yT, out, out, out, 1);
}

// Round 5
// 104.918 us; speedup vs baseline: 54.5717x; 1.3460x over previous
//
#include <hip/hip_runtime.h>
#include <hip/hip_bf16.h>
#include <math.h>

#define B_ 8
#define C_ 256
#define N_ 1024
#define H_ 8
#define DH 96
#define BHN (C_*3*N_)
#define SC 0.10206207261596575f   // 1/sqrt(96)

typedef _Float16 half8 __attribute__((ext_vector_type(8)));
typedef float f32x4 __attribute__((ext_vector_type(4)));
typedef float f32x16 __attribute__((ext_vector_type(16)));

typedef __attribute__((address_space(1))) void gvoid;
typedef __attribute__((address_space(3))) void lvoid;
__device__ inline void gl_lds16(const _Float16* g, _Float16* l) {
  __builtin_amdgcn_global_load_lds((gvoid*)g, (lvoid*)l, 16, 0, 0);
}

typedef __fp16 fp16x2 __attribute__((ext_vector_type(2)));
union H2U { fp16x2 h2; unsigned u; };
__device__ inline unsigned pkh(float a, float b) {
  H2U x; x.h2 = __builtin_amdgcn_cvt_pkrtz(a, b); return x.u;
}
union PF { half8 v; unsigned u[4]; };

// ---------------------------------------------------------------------------
// Mask -> per-64-key-tile uint64 bitmask: mb[b*16 + t], bit j = key t*64+j pad
// ---------------------------------------------------------------------------
__global__ void mask_bits_kernel(const unsigned* __restrict__ mraw,
                                 unsigned long long* __restrict__ mb) {
  __shared__ int notI, notF;
  if (threadIdx.x == 0) { notI = 0; notF = 0; }
  __syncthreads();
  int li = 0, lf = 0;
  for (int i = threadIdx.x; i < 2048; i += 256) {
    unsigned w = mraw[i];
    if (w > 1u) li = 1;
    if (w != 0u && w != 0x3F800000u) lf = 1;
  }
  if (li) atomicOr(&notI, 1);
  if (lf) atomicOr(&notF, 1);
  __syncthreads();
  const int tid = threadIdx.x;
  if (tid < 128) {
    int base = tid * 64;  // element index b*1024 + t*64
    unsigned long long bits = 0;
    if (!notI) {
      for (int j = 0; j < 64; ++j)
        bits |= (unsigned long long)(mraw[base + j] & 1u) << j;
    } else if (!notF) {
      for (int j = 0; j < 64; ++j)
        bits |= (unsigned long long)(mraw[base + j] != 0u ? 1 : 0) << j;
    } else {
      const unsigned char* m8 = (const unsigned char*)mraw;
      for (int j = 0; j < 64; ++j)
        bits |= (unsigned long long)(m8[base + j] ? 1 : 0) << j;
    }
    mb[tid] = bits;
  }
}

// ---------------------------------------------------------------------------
// Weights fp32 -> fp16 [4][256][256]
// ---------------------------------------------------------------------------
__global__ void convw_kernel(const float* __restrict__ Wq,
                             const float* __restrict__ Wk,
                             const float* __restrict__ Wv,
                             const float* __restrict__ Wp,
                             _Float16* __restrict__ Wh) {
  int idx = blockIdx.x * 256 + threadIdx.x;
  int e0 = idx * 8;
  const float* src = (e0 < 65536) ? Wq
                   : (e0 < 131072) ? Wk
                   : (e0 < 196608) ? Wv : Wp;
  int off = e0 & 65535;
  float4 a = *(const float4*)&src[off];
  float4 b = *(const float4*)&src[off + 4];
  _Float16 t[8] = {(_Float16)a.x, (_Float16)a.y, (_Float16)a.z, (_Float16)a.w,
                   (_Float16)b.x, (_Float16)b.y, (_Float16)b.z, (_Float16)b.w};
  *(uint4*)&Wh[e0] = *(uint4*)t;
}

// ---------------------------------------------------------------------------
// x [b][256][3072] fp32 -> XT [b][3072][256] fp16 (n-major)
// ---------------------------------------------------------------------------
__global__ __launch_bounds__(256) void convxt_kernel(
    const float* __restrict__ x, _Float16* __restrict__ XT) {
  __shared__ _Float16 T[64][65];
  const int m0 = blockIdx.x * 64;
  const int c0 = blockIdx.y * 64;
  const int b = blockIdx.z;
  const float* xb = x + (size_t)b * BHN;
  _Float16* ob = XT + (size_t)b * BHN;
  const int t = threadIdx.x;
#pragma unroll
  for (int i = 0; i < 16; ++i) {
    int e = t + i * 256;
    int c = e >> 6, m = e & 63;
    T[m][c] = (_Float16)xb[(size_t)(c0 + c) * 3072 + m0 + m];
  }
  __syncthreads();
#pragma unroll
  for (int i = 0; i < 2; ++i) {
    int e = t + i * 256;
    int m = e >> 3, ch = e & 7;
    _Float16 tmp[8];
#pragma unroll
    for (int j = 0; j < 8; ++j) tmp[j] = T[m][ch * 8 + j];
    *(uint4*)&ob[(size_t)(m0 + m) * 256 + c0 + ch * 8] = *(uint4*)tmp;
  }
}

// ---------------------------------------------------------------------------
// fp16 MFMA GEMM: O = W(256x256) @ X[b](256x3072), X n-major [n][c].
// MODE 0: w=0 -> O0 n-major fp16 *SC (q); w=1 -> O1 n-major fp16 (k);
//         w=2 -> O2 c-major fp16 (v).
// MODE 1: Of c-major fp32 (final out).
// ---------------------------------------------------------------------------
template <int MODE>
__global__ __launch_bounds__(256, 4) void mgemm_kernel(
    const _Float16* __restrict__ Wh, int woff,
    const _Float16* __restrict__ Xn,
    _Float16* __restrict__ O0, _Float16* __restrict__ O1,
    _Float16* __restrict__ O2, float* __restrict__ Of, int nw) {
  const int zz = blockIdx.z;
  const int w = zz % nw;
  const int b = zz / nw;
  const _Float16* Wb = Wh + (size_t)(woff + w) * 65536;
  const _Float16* Bb = Xn + (size_t)b * BHN;
  const int o0 = blockIdx.y * 128;
  const int bn0 = blockIdx.x * 128;

  __shared__ __align__(16) _Float16 Ah[4096];  // [128][32]
  __shared__ __align__(16) _Float16 Bh[4096];  // [128][32]

  const int tid = threadIdx.x;
  const int wave = tid >> 6;
  const int lane = tid & 63;
  const int lg = lane >> 4, ll = lane & 15;
  const int wm = wave >> 1, wn = wave & 1;
  const int r0 = tid >> 2, c4 = tid & 3;

  f32x4 acc[4][4];
#pragma unroll
  for (int mi = 0; mi < 4; ++mi)
#pragma unroll
    for (int ni = 0; ni < 4; ++ni) acc[mi][ni] = (f32x4){0.f, 0.f, 0.f, 0.f};

  for (int k0 = 0; k0 < 256; k0 += 32) {
    gl_lds16(Wb + (size_t)(o0 + r0) * 256 + k0 + c4 * 8, &Ah[wave * 512]);
    gl_lds16(Wb + (size_t)(o0 + 64 + r0) * 256 + k0 + c4 * 8,
             &Ah[2048 + wave * 512]);
    gl_lds16(Bb + (size_t)(bn0 + r0) * 256 + k0 + c4 * 8, &Bh[wave * 512]);
    gl_lds16(Bb + (size_t)(bn0 + 64 + r0) * 256 + k0 + c4 * 8,
             &Bh[2048 + wave * 512]);
    __syncthreads();
    half8 af[4], bf[4];
#pragma unroll
    for (int mi = 0; mi < 4; ++mi)
      af[mi] = *(const half8*)&Ah[(wm * 64 + mi * 16 + ll) * 32 + lg * 8];
#pragma unroll
    for (int ni = 0; ni < 4; ++ni)
      bf[ni] = *(const half8*)&Bh[(wn * 64 + ni * 16 + ll) * 32 + lg * 8];
#pragma unroll
    for (int mi = 0; mi < 4; ++mi)
#pragma unroll
      for (int ni = 0; ni < 4; ++ni)
        acc[mi][ni] = __builtin_amdgcn_mfma_f32_16x16x32_f16(
            af[mi], bf[ni], acc[mi][ni], 0, 0, 0);
    __syncthreads();
  }

#pragma unroll
  for (int mi = 0; mi < 4; ++mi) {
#pragma unroll
    for (int ni = 0; ni < 4; ++ni) {
      int o = o0 + wm * 64 + mi * 16 + lg * 4;
      int n = bn0 + wn * 64 + ni * 16 + ll;
      if constexpr (MODE == 1) {
        float* Ofb = Of + (size_t)b * BHN;
#pragma unroll
        for (int r = 0; r < 4; ++r)
          Ofb[(size_t)(o + r) * 3072 + n] = acc[mi][ni][r];
      } else {
        if (w == 2) {
          _Float16* Oc = O2 + (size_t)b * BHN;
#pragma unroll
          for (int r = 0; r < 4; ++r)
            Oc[(size_t)(o + r) * 3072 + n] = (_Float16)acc[mi][ni][r];
        } else {
          _Float16* On = ((w == 0) ? O0 : O1) + (size_t)b * BHN;
          float qs = (w == 0) ? SC : 1.0f;
          _Float16 t4[4];
#pragma unroll
          for (int r = 0; r < 4; ++r) t4[r] = (_Float16)(acc[mi][ni][r] * qs);
          *(uint2*)&On[(size_t)n * 256 + o] = *(uint2*)t4;
        }
      }
    }
  }
}

// ---------------------------------------------------------------------------
// Flash attention, 32x32 swapped-QK^T, in-register softmax, P in-register.
// q,k n-major [b][3n][256] fp16 (q pre-scaled); v c-major [b][256][3n] fp16.
// yT out n-major fp16. Block = 4 waves x 32 q-rows = 128 q. 512 blocks.
// d-perm convention: dperm = dd*32 + i  (d = i*3+dd, c = h*32+i).
// LDS chunk-column-major [chunk][row][8 halves] -> bank-even ds_read_b128.
// C/D map (HW-verified): col=lane&31, row=(r&3)+8*(r>>2)+4*(lane>>5).
// ---------------------------------------------------------------------------
__global__ __launch_bounds__(256, 2) void attn_kernel(
    const _Float16* __restrict__ qh, const _Float16* __restrict__ kh,
    const _Float16* __restrict__ vh,
    const unsigned long long* __restrict__ mbits,
    _Float16* __restrict__ yT) {
  const int gid = blockIdx.x;
  const int bh = gid & 63;   // XCD = bh%8 = h -> all q-tiles+batches of head co-XCD
  const int qt = gid >> 6;
  const int b = bh >> 3, h = bh & 7;
  const int n0 = qt * 128;

  __shared__ __align__(16) _Float16 Qs[12288];  // [p12][q128][8] 24KB; Ys later
  __shared__ __align__(16) _Float16 Ks[6144];   // [p12][key64][8] 12KB
  __shared__ __align__(16) _Float16 Vt[6144];   // [kp8][d96][8]  12KB

  const int tid = threadIdx.x;
  const int lane = tid & 63;
  const int wave = tid >> 6;
  const int hi = lane >> 5;
  const int lq = lane & 31;
  const int wq0 = wave * 32;

  const _Float16* qb = qh + (size_t)b * BHN;
  const _Float16* kb = kh + (size_t)b * BHN;
  const _Float16* vb = vh + (size_t)b * BHN;

  // ---- stage Q: 6 rounds; round r stages chunk-row p = (r*4+wave) of
  // [p][q] layout ----
#pragma unroll
  for (int r = 0; r < 6; ++r) {
    int pc = r * 4 + wave;          // 0..23
    int p = pc >> 1;                // chunk-row p (0..11)
    int q = (pc & 1) * 64 + lane;   // q row (0..127)
    gl_lds16(qb + (size_t)((p >> 2) * 1024 + n0 + q) * 256 + h * 32 + (p & 3) * 8,
             &Qs[(r * 4 + wave) * 512]);
  }
  __syncthreads();

  // ---- Q fragments: qf[ks]: Q[q=wq0+lq][d = ks*16 + hi*8 .. +8] ----
  half8 qf[6];
#pragma unroll
  for (int ks = 0; ks < 6; ++ks)
    qf[ks] = *(const half8*)&Qs[(((2 * ks + hi) * 128) + wq0 + lq) * 8];

  // ---- staging address precompute ----
  const _Float16* ksrc[3];
  const _Float16* vsrc[3];
#pragma unroll
  for (int r = 0; r < 3; ++r) {
    int p = r * 4 + wave;  // K chunk-row; key = lane
    ksrc[r] = kb + (size_t)((p >> 2) * 1024 + lane) * 256 + h * 32 + (p & 3) * 8;
    int G = (r * 4 + wave) * 64 + lane;  // V chunk id
    int kp = G / 96, d = G - kp * 96;    // Vt[kp][d]
    vsrc[r] = vb + (size_t)(h * 32 + (d & 31)) * 3072 + (d >> 5) * 1024 + kp * 8;
  }

  float M = 0.f, L = 0.f;
  f32x16 yacc[3];
#pragma unroll
  for (int dt = 0; dt < 3; ++dt)
#pragma unroll
    for (int r = 0; r < 16; ++r) yacc[dt][r] = 0.f;

  for (int t = 0; t < 16; ++t) {
    __syncthreads();  // previous tile's reads done
#pragma unroll
    for (int r = 0; r < 3; ++r) {
      gl_lds16(ksrc[r], &Ks[(r * 4 + wave) * 512]);
      gl_lds16(vsrc[r], &Vt[(r * 4 + wave) * 512]);
      ksrc[r] += 64 * 256;  // next 64 key rows
      vsrc[r] += 64;        // next 64 keys within row
    }
    __syncthreads();  // staging visible (vmcnt drained by barrier)

    const unsigned long long m64 = mbits[b * 16 + t];

    // ---- S = K.Q^T (swapped): s[nt] rows=keys nt*32.., cols=q ----
    f32x16 s[2];
#pragma unroll
    for (int r = 0; r < 16; ++r) { s[0][r] = 0.f; s[1][r] = 0.f; }
#pragma unroll
    for (int ks = 0; ks < 6; ++ks) {
      half8 kf0 = *(const half8*)&Ks[(((2 * ks + hi) * 64) + lq) * 8];
      half8 kf1 = *(const half8*)&Ks[(((2 * ks + hi) * 64) + 32 + lq) * 8];
      s[0] = __builtin_amdgcn_mfma_f32_32x32x16_f16(kf0, qf[ks], s[0], 0, 0, 0);
      s[1] = __builtin_amdgcn_mfma_f32_32x32x16_f16(kf1, qf[ks], s[1], 0, 0, 0);
    }

    // ---- mask + online softmax (lane owns q-row lq; keys split by hi) ----
    float mx = -1e30f;
#pragma unroll
    for (int nt = 0; nt < 2; ++nt) {
      unsigned wm = (unsigned)(m64 >> (nt * 32 + 4 * hi));
#pragma unroll
      for (int r = 0; r < 16; ++r) {
        float sv = s[nt][r];
        sv = ((wm >> ((r & 3) + 8 * (r >> 2))) & 1u) ? -1e30f : sv;
        s[nt][r] = sv;
        mx = fmaxf(mx, sv);
      }
    }
    mx = fmaxf(mx, __shfl_xor(mx, 32));
    float newM = fmaxf(M, mx);
    float corr = __expf(M - newM);
    M = newM;
    float psum = 0.f;
#pragma unroll
    for (int nt = 0; nt < 2; ++nt)
#pragma unroll
      for (int r = 0; r < 16; ++r) {
        float p = __expf(s[nt][r] - newM);
        s[nt][r] = p;
        psum += p;
      }
    psum += __shfl_xor(psum, 32);
    L = L * corr + psum;
#pragma unroll
    for (int dt = 0; dt < 3; ++dt)
#pragma unroll
      for (int r = 0; r < 16; ++r) yacc[dt][r] *= corr;

    // ---- P -> fp16 B-fragments in-register (half-swap), PV accumulate ----
#pragma unroll
    for (int nt = 0; nt < 2; ++nt) {
#pragma unroll
      for (int hf = 0; hf < 2; ++hf) {
        const int bs = hf * 8;
        unsigned A0 = pkh(s[nt][bs + 0], s[nt][bs + 1]);
        unsigned A1 = pkh(s[nt][bs + 2], s[nt][bs + 3]);
        unsigned B0 = pkh(s[nt][bs + 4], s[nt][bs + 5]);
        unsigned B1 = pkh(s[nt][bs + 6], s[nt][bs + 7]);
        unsigned xA0 = (unsigned)__shfl_xor((int)A0, 32);
        unsigned xA1 = (unsigned)__shfl_xor((int)A1, 32);
        unsigned xB0 = (unsigned)__shfl_xor((int)B0, 32);
        unsigned xB1 = (unsigned)__shfl_xor((int)B1, 32);
        PF pf;
        pf.u[0] = hi ? xB0 : A0;
        pf.u[1] = hi ? xB1 : A1;
        pf.u[2] = hi ? B0 : xA0;
        pf.u[3] = hi ? B1 : xA1;
        const int kt = nt * 2 + hf;
#pragma unroll
        for (int dt = 0; dt < 3; ++dt) {
          half8 vf = *(const half8*)&Vt[(((kt * 2 + hi) * 96) + dt * 32 + lq) * 8];
          yacc[dt] = __builtin_amdgcn_mfma_f32_32x32x16_f16(vf, pf.v, yacc[dt],
                                                            0, 0, 0);
        }
      }
    }
  }

  // ---- epilogue: normalize, stage per-wave [q32][96] in Qs, write n-major ----
  float inv = (L > 0.f) ? 1.f / L : 0.f;
  _Float16* Ys = &Qs[wave * 3072];
#pragma unroll
  for (int dt = 0; dt < 3; ++dt)
#pragma unroll
    for (int r = 0; r < 16; ++r) {
      int dperm = dt * 32 + (r & 3) + 8 * (r >> 2) + 4 * hi;
      Ys[lq * 96 + dperm] = (_Float16)(yacc[dt][r] * inv);
    }
  // wave-local region; DS is in-order per wave -> no barrier needed
  _Float16* yb = yT + (size_t)b * BHN;
#pragma unroll
  for (int j = 0; j < 6; ++j) {
    int c = j * 64 + lane;           // 0..383: chunk = q*12 + p
    int q = c / 12, p = c - q * 12;
    uint4 val = *(const uint4*)&Ys[q * 96 + p * 8];
    int dd = p >> 2, pi = p & 3;
    *(uint4*)&yb[(size_t)((dd << 10) + n0 + wq0 + q) * 256 + h * 32 + pi * 8] =
        val;
  }
}

// ---------------------------------------------------------------------------
extern "C" void kernel_launch(void* const* d_in, const int* in_sizes, int n_in,
                              void* d_out, int out_size, void* d_ws,
                              size_t ws_size, hipStream_t stream) {
  const float* x = (const float*)d_in[0];
  const float* Wq = (const float*)d_in[1];
  const float* Wk = (const float*)d_in[2];
  const float* Wv = (const float*)d_in[3];
  const float* Wp = (const float*)d_in[4];
  const unsigned* mask = (const unsigned*)d_in[5];
  float* out = (float*)d_out;

  _Float16* Wh = (_Float16*)d_ws;                   // 0.5 MB
  _Float16* XT = Wh + 4 * 65536;                    // 12.6 MB n-major
  _Float16* qh = XT + (size_t)B_ * BHN;             // 12.6 MB n-major (scaled)
  _Float16* kh = qh + (size_t)B_ * BHN;             // 12.6 MB n-major
  _Float16* vh = kh + (size_t)B_ * BHN;             // 12.6 MB c-major
  _Float16* yT = vh + (size_t)B_ * BHN;             // 12.6 MB n-major
  unsigned long long* mb = (unsigned long long*)(yT + (size_t)B_ * BHN);

  mask_bits_kernel<<<1, 256, 0, stream>>>(mask, mb);
  convw_kernel<<<128, 256, 0, stream>>>(Wq, Wk, Wv, Wp, Wh);
  convxt_kernel<<<dim3(48, 4, B_), 256, 0, stream>>>(x, XT);

  dim3 g1(24, 2, B_ * 3);
  mgemm_kernel<0><<<g1, 256, 0, stream>>>(Wh, 0, XT, qh, kh, vh, nullptr, 3);

  attn_kernel<<<dim3(512), 256, 0, stream>>>(qh, kh, vh, mb, yT);

  dim3 g3(24, 2, B_);
  mgemm_kernel<1><<<g3, 256, 0, stream>>>(Wh, 3, yT, nullptr, nullptr, nullptr,
                                          out, 1);
}

// Round 6
// 101.589 us; speedup vs baseline: 56.3603x; 1.0328x over previous
//
#include <hip/hip_runtime.h>
#include <hip/hip_bf16.h>
#include <math.h>

#define B_ 8
#define C_ 256
#define N_ 1024
#define H_ 8
#define DH 96
#define BHN (C_*3*N_)
#define SC 0.10206207261596575f   // 1/sqrt(96)

typedef _Float16 half8 __attribute__((ext_vector_type(8)));
typedef float f32x4 __attribute__((ext_vector_type(4)));
typedef float f32x16 __attribute__((ext_vector_type(16)));

typedef __attribute__((address_space(1))) void gvoid;
typedef __attribute__((address_space(3))) void lvoid;
__device__ inline void gl_lds16(const _Float16* g, _Float16* l) {
  __builtin_amdgcn_global_load_lds((gvoid*)g, (lvoid*)l, 16, 0, 0);
}

typedef __fp16 fp16x2 __attribute__((ext_vector_type(2)));
union H2U { fp16x2 h2; unsigned u; };
__device__ inline unsigned pkh(float a, float b) {
  H2U x; x.h2 = __builtin_amdgcn_cvt_pkrtz(a, b); return x.u;
}
union PF { half8 v; unsigned u[4]; };

// v_permlane32_swap_b32: a_hi <-> b_lo  =>  a' = [a_lo|b_lo], b' = [a_hi|b_hi]
__device__ inline void plswap(unsigned& a, unsigned& b) {
  asm volatile("v_permlane32_swap_b32 %0, %1" : "+v"(a), "+v"(b));
}

// ---------------------------------------------------------------------------
// Mask -> per-64-key-tile uint64 bitmask: mb[b*16 + t], bit j = key t*64+j pad
// ---------------------------------------------------------------------------
__global__ void mask_bits_kernel(const unsigned* __restrict__ mraw,
                                 unsigned long long* __restrict__ mb) {
  __shared__ int notI, notF;
  if (threadIdx.x == 0) { notI = 0; notF = 0; }
  __syncthreads();
  int li = 0, lf = 0;
  for (int i = threadIdx.x; i < 2048; i += 256) {
    unsigned w = mraw[i];
    if (w > 1u) li = 1;
    if (w != 0u && w != 0x3F800000u) lf = 1;
  }
  if (li) atomicOr(&notI, 1);
  if (lf) atomicOr(&notF, 1);
  __syncthreads();
  const int tid = threadIdx.x;
  if (tid < 128) {
    int base = tid * 64;
    unsigned long long bits = 0;
    if (!notI) {
      for (int j = 0; j < 64; ++j)
        bits |= (unsigned long long)(mraw[base + j] & 1u) << j;
    } else if (!notF) {
      for (int j = 0; j < 64; ++j)
        bits |= (unsigned long long)(mraw[base + j] != 0u ? 1 : 0) << j;
    } else {
      const unsigned char* m8 = (const unsigned char*)mraw;
      for (int j = 0; j < 64; ++j)
        bits |= (unsigned long long)(m8[base + j] ? 1 : 0) << j;
    }
    mb[tid] = bits;
  }
}

// ---------------------------------------------------------------------------
// Weights fp32 -> fp16 [4][256][256]
// ---------------------------------------------------------------------------
__global__ void convw_kernel(const float* __restrict__ Wq,
                             const float* __restrict__ Wk,
                             const float* __restrict__ Wv,
                             const float* __restrict__ Wp,
                             _Float16* __restrict__ Wh) {
  int idx = blockIdx.x * 256 + threadIdx.x;
  int e0 = idx * 8;
  const float* src = (e0 < 65536) ? Wq
                   : (e0 < 131072) ? Wk
                   : (e0 < 196608) ? Wv : Wp;
  int off = e0 & 65535;
  float4 a = *(const float4*)&src[off];
  float4 b = *(const float4*)&src[off + 4];
  _Float16 t[8] = {(_Float16)a.x, (_Float16)a.y, (_Float16)a.z, (_Float16)a.w,
                   (_Float16)b.x, (_Float16)b.y, (_Float16)b.z, (_Float16)b.w};
  *(uint4*)&Wh[e0] = *(uint4*)t;
}

// ---------------------------------------------------------------------------
// x [b][256][3072] fp32 -> XT [b][3072][256] fp16 (n-major)
// ---------------------------------------------------------------------------
__global__ __launch_bounds__(256) void convxt_kernel(
    const float* __restrict__ x, _Float16* __restrict__ XT) {
  __shared__ _Float16 T[64][65];
  const int m0 = blockIdx.x * 64;
  const int c0 = blockIdx.y * 64;
  const int b = blockIdx.z;
  const float* xb = x + (size_t)b * BHN;
  _Float16* ob = XT + (size_t)b * BHN;
  const int t = threadIdx.x;
#pragma unroll
  for (int i = 0; i < 16; ++i) {
    int e = t + i * 256;
    int c = e >> 6, m = e & 63;
    T[m][c] = (_Float16)xb[(size_t)(c0 + c) * 3072 + m0 + m];
  }
  __syncthreads();
#pragma unroll
  for (int i = 0; i < 2; ++i) {
    int e = t + i * 256;
    int m = e >> 3, ch = e & 7;
    _Float16 tmp[8];
#pragma unroll
    for (int j = 0; j < 8; ++j) tmp[j] = T[m][ch * 8 + j];
    *(uint4*)&ob[(size_t)(m0 + m) * 256 + c0 + ch * 8] = *(uint4*)tmp;
  }
}

// ---------------------------------------------------------------------------
// fp16 MFMA GEMM: O = W(256x256) @ X[b](256x3072), X n-major [n][c].
// MODE 0: w=0 -> O0 n-major fp16 *SC (q); w=1 -> O1 n-major fp16 (k);
//         w=2 -> O2 c-major fp16 (v).
// MODE 1: Of c-major fp32 (final out).
// ---------------------------------------------------------------------------
template <int MODE>
__global__ __launch_bounds__(256, 4) void mgemm_kernel(
    const _Float16* __restrict__ Wh, int woff,
    const _Float16* __restrict__ Xn,
    _Float16* __restrict__ O0, _Float16* __restrict__ O1,
    _Float16* __restrict__ O2, float* __restrict__ Of, int nw) {
  const int zz = blockIdx.z;
  const int w = zz % nw;
  const int b = zz / nw;
  const _Float16* Wb = Wh + (size_t)(woff + w) * 65536;
  const _Float16* Bb = Xn + (size_t)b * BHN;
  const int o0 = blockIdx.y * 128;
  const int bn0 = blockIdx.x * 128;

  __shared__ __align__(16) _Float16 Ah[4096];  // [128][32]
  __shared__ __align__(16) _Float16 Bh[4096];  // [128][32]

  const int tid = threadIdx.x;
  const int wave = tid >> 6;
  const int lane = tid & 63;
  const int lg = lane >> 4, ll = lane & 15;
  const int wm = wave >> 1, wn = wave & 1;
  const int r0 = tid >> 2, c4 = tid & 3;

  f32x4 acc[4][4];
#pragma unroll
  for (int mi = 0; mi < 4; ++mi)
#pragma unroll
    for (int ni = 0; ni < 4; ++ni) acc[mi][ni] = (f32x4){0.f, 0.f, 0.f, 0.f};

  for (int k0 = 0; k0 < 256; k0 += 32) {
    gl_lds16(Wb + (size_t)(o0 + r0) * 256 + k0 + c4 * 8, &Ah[wave * 512]);
    gl_lds16(Wb + (size_t)(o0 + 64 + r0) * 256 + k0 + c4 * 8,
             &Ah[2048 + wave * 512]);
    gl_lds16(Bb + (size_t)(bn0 + r0) * 256 + k0 + c4 * 8, &Bh[wave * 512]);
    gl_lds16(Bb + (size_t)(bn0 + 64 + r0) * 256 + k0 + c4 * 8,
             &Bh[2048 + wave * 512]);
    __syncthreads();
    half8 af[4], bf[4];
#pragma unroll
    for (int mi = 0; mi < 4; ++mi)
      af[mi] = *(const half8*)&Ah[(wm * 64 + mi * 16 + ll) * 32 + lg * 8];
#pragma unroll
    for (int ni = 0; ni < 4; ++ni)
      bf[ni] = *(const half8*)&Bh[(wn * 64 + ni * 16 + ll) * 32 + lg * 8];
#pragma unroll
    for (int mi = 0; mi < 4; ++mi)
#pragma unroll
      for (int ni = 0; ni < 4; ++ni)
        acc[mi][ni] = __builtin_amdgcn_mfma_f32_16x16x32_f16(
            af[mi], bf[ni], acc[mi][ni], 0, 0, 0);
    __syncthreads();
  }

#pragma unroll
  for (int mi = 0; mi < 4; ++mi) {
#pragma unroll
    for (int ni = 0; ni < 4; ++ni) {
      int o = o0 + wm * 64 + mi * 16 + lg * 4;
      int n = bn0 + wn * 64 + ni * 16 + ll;
      if constexpr (MODE == 1) {
        float* Ofb = Of + (size_t)b * BHN;
#pragma unroll
        for (int r = 0; r < 4; ++r)
          Ofb[(size_t)(o + r) * 3072 + n] = acc[mi][ni][r];
      } else {
        if (w == 2) {
          _Float16* Oc = O2 + (size_t)b * BHN;
#pragma unroll
          for (int r = 0; r < 4; ++r)
            Oc[(size_t)(o + r) * 3072 + n] = (_Float16)acc[mi][ni][r];
        } else {
          _Float16* On = ((w == 0) ? O0 : O1) + (size_t)b * BHN;
          float qs = (w == 0) ? SC : 1.0f;
          _Float16 t4[4];
#pragma unroll
          for (int r = 0; r < 4; ++r) t4[r] = (_Float16)(acc[mi][ni][r] * qs);
          *(uint2*)&On[(size_t)n * 256 + o] = *(uint2*)t4;
        }
      }
    }
  }
}

// ---------------------------------------------------------------------------
// Flash attention, 32x32 swapped-QK^T, in-register softmax + P repack via
// v_permlane32_swap. Double-buffered K/V: stage tile t+1 right after the
// per-tile __syncthreads (its vmcnt-drain covers loads issued one full tile
// earlier -> HBM latency hidden). Deferred-max (THR=8), per-half L.
// C/D map (HW-verified): col=lane&31, row=(r&3)+8*(r>>2)+4*(lane>>5).
// ---------------------------------------------------------------------------
__global__ __launch_bounds__(256, 2) void attn_kernel(
    const _Float16* __restrict__ qh, const _Float16* __restrict__ kh,
    const _Float16* __restrict__ vh,
    const unsigned long long* __restrict__ mbits,
    _Float16* __restrict__ yT) {
  const int gid = blockIdx.x;
  const int bh = gid & 63;   // XCD = bh%8 = h
  const int qt = gid >> 6;
  const int b = bh >> 3, h = bh & 7;
  const int n0 = qt * 128;

  __shared__ __align__(16) _Float16 Qs[12288];     // [p12][q128][8]; Ys later
  __shared__ __align__(16) _Float16 KsL[2][6144];  // dbuf [p12][key64][8]
  __shared__ __align__(16) _Float16 VtL[2][6144];  // dbuf [kp8][d96][8]

  const int tid = threadIdx.x;
  const int lane = tid & 63;
  const int wave = tid >> 6;
  const int hi = lane >> 5;
  const int lq = lane & 31;
  const int wq0 = wave * 32;

  const _Float16* qb = qh + (size_t)b * BHN;
  const _Float16* kb = kh + (size_t)b * BHN;
  const _Float16* vb = vh + (size_t)b * BHN;

  // staging source pointers (self-advancing, one tile per stage_kv call)
  const _Float16* ksrc[3];
  const _Float16* vsrc[3];
#pragma unroll
  for (int r = 0; r < 3; ++r) {
    int p = r * 4 + wave;
    ksrc[r] = kb + (size_t)((p >> 2) * 1024 + lane) * 256 + h * 32 + (p & 3) * 8;
    int G = (r * 4 + wave) * 64 + lane;
    int kp = G / 96, d = G - kp * 96;
    vsrc[r] = vb + (size_t)(h * 32 + (d & 31)) * 3072 + (d >> 5) * 1024 + kp * 8;
  }

  auto stage_kv = [&](int cur) {
    _Float16* Kd = &KsL[cur][0];
    _Float16* Vd = &VtL[cur][0];
#pragma unroll
    for (int r = 0; r < 3; ++r) {
      gl_lds16(ksrc[r], &Kd[(r * 4 + wave) * 512]);
      gl_lds16(vsrc[r], &Vd[(r * 4 + wave) * 512]);
      ksrc[r] += 64 * 256;
      vsrc[r] += 64;
    }
  };

  // ---- prologue: stage Q + first K/V tile, one drain ----
#pragma unroll
  for (int r = 0; r < 6; ++r) {
    int pc = r * 4 + wave;
    int p = pc >> 1;
    int q = (pc & 1) * 64 + lane;
    gl_lds16(qb + (size_t)((p >> 2) * 1024 + n0 + q) * 256 + h * 32 + (p & 3) * 8,
             &Qs[(r * 4 + wave) * 512]);
  }
  stage_kv(0);
  __syncthreads();
  stage_kv(1);  // tile 1 lands while tile 0 computes

  half8 qf[6];
#pragma unroll
  for (int ks = 0; ks < 6; ++ks)
    qf[ks] = *(const half8*)&Qs[(((2 * ks + hi) * 128) + wq0 + lq) * 8];

  float M = 0.f, Lh = 0.f;
  f32x16 yacc[3];
#pragma unroll
  for (int dt = 0; dt < 3; ++dt)
#pragma unroll
    for (int r = 0; r < 16; ++r) yacc[dt][r] = 0.f;

  auto compute_tile = [&](int t, int cur) {
    const _Float16* Ksb = &KsL[cur][0];
    const _Float16* Vtb = &VtL[cur][0];
    const unsigned long long m64 = mbits[b * 16 + t];

    // ---- S = K.Q^T (swapped): rows=keys, cols=q ----
    f32x16 s[2];
#pragma unroll
    for (int r = 0; r < 16; ++r) { s[0][r] = 0.f; s[1][r] = 0.f; }
    __builtin_amdgcn_s_setprio(1);
#pragma unroll
    for (int ks = 0; ks < 6; ++ks) {
      half8 kf0 = *(const half8*)&Ksb[(((2 * ks + hi) * 64) + lq) * 8];
      half8 kf1 = *(const half8*)&Ksb[(((2 * ks + hi) * 64) + 32 + lq) * 8];
      s[0] = __builtin_amdgcn_mfma_f32_32x32x16_f16(kf0, qf[ks], s[0], 0, 0, 0);
      s[1] = __builtin_amdgcn_mfma_f32_32x32x16_f16(kf1, qf[ks], s[1], 0, 0, 0);
    }
    __builtin_amdgcn_s_setprio(0);

    // ---- mask + local max ----
    float mx = -1e30f;
#pragma unroll
    for (int nt = 0; nt < 2; ++nt) {
      unsigned wm = (unsigned)(m64 >> (nt * 32 + 4 * hi));
#pragma unroll
      for (int r = 0; r < 16; ++r) {
        float sv = s[nt][r];
        sv = ((wm >> ((r & 3) + 8 * (r >> 2))) & 1u) ? -1e30f : sv;
        s[nt][r] = sv;
        mx = fmaxf(mx, sv);
      }
    }
    // ---- deferred max (THR=8): rescale only when needed ----
    if (__any(mx > M + 8.f)) {
      float mx2 = fmaxf(mx, __shfl_xor(mx, 32));
      float newM = fmaxf(M, mx2);
      float corr = __expf(M - newM);
      M = newM;
      Lh *= corr;
#pragma unroll
      for (int dt = 0; dt < 3; ++dt)
#pragma unroll
        for (int r = 0; r < 16; ++r) yacc[dt][r] *= corr;
    }
    float psum = 0.f;
#pragma unroll
    for (int nt = 0; nt < 2; ++nt)
#pragma unroll
      for (int r = 0; r < 16; ++r) {
        float p = __expf(s[nt][r] - M);
        s[nt][r] = p;
        psum += p;
      }
    Lh += psum;

    // ---- P -> fp16 B-frags via permlane32_swap, PV accumulate ----
#pragma unroll
    for (int nt = 0; nt < 2; ++nt) {
#pragma unroll
      for (int hf = 0; hf < 2; ++hf) {
        const int bs = hf * 8;
        unsigned A0 = pkh(s[nt][bs + 0], s[nt][bs + 1]);
        unsigned A1 = pkh(s[nt][bs + 2], s[nt][bs + 3]);
        unsigned B0 = pkh(s[nt][bs + 4], s[nt][bs + 5]);
        unsigned B1 = pkh(s[nt][bs + 6], s[nt][bs + 7]);
        plswap(A0, B0);  // A0'=[A0lo|B0lo] (pf lo), B0'=[A0hi|B0hi] (pf hi)
        plswap(A1, B1);
        PF pf;
        pf.u[0] = A0;
        pf.u[1] = A1;
        pf.u[2] = B0;
        pf.u[3] = B1;
        const int kt = nt * 2 + hf;
        __builtin_amdgcn_s_setprio(1);
#pragma unroll
        for (int dt = 0; dt < 3; ++dt) {
          half8 vf = *(const half8*)&Vtb[(((kt * 2 + hi) * 96) + dt * 32 + lq) * 8];
          yacc[dt] = __builtin_amdgcn_mfma_f32_32x32x16_f16(vf, pf.v, yacc[dt],
                                                            0, 0, 0);
        }
        __builtin_amdgcn_s_setprio(0);
      }
    }
  };

  compute_tile(0, 0);
  for (int t = 1; t < 16; ++t) {
    __syncthreads();             // drains stage(t) (issued one tile ago)
    if (t + 1 < 16) stage_kv((t + 1) & 1);  // lands during compute(t)
    compute_tile(t, t & 1);
  }

  // ---- epilogue ----
  float L = Lh + __shfl_xor(Lh, 32);
  float inv = (L > 0.f) ? 1.f / L : 0.f;
  _Float16* Ys = &Qs[wave * 3072];
#pragma unroll
  for (int dt = 0; dt < 3; ++dt)
#pragma unroll
    for (int r = 0; r < 16; ++r) {
      int dperm = dt * 32 + (r & 3) + 8 * (r >> 2) + 4 * hi;
      Ys[lq * 96 + dperm] = (_Float16)(yacc[dt][r] * inv);
    }
  // wave-local region; DS in-order per wave -> no barrier needed
  _Float16* yb = yT + (size_t)b * BHN;
#pragma unroll
  for (int j = 0; j < 6; ++j) {
    int c = j * 64 + lane;
    int q = c / 12, p = c - q * 12;
    uint4 val = *(const uint4*)&Ys[q * 96 + p * 8];
    int dd = p >> 2, pi = p & 3;
    *(uint4*)&yb[(size_t)((dd << 10) + n0 + wq0 + q) * 256 + h * 32 + pi * 8] =
        val;
  }
}

// ---------------------------------------------------------------------------
extern "C" void kernel_launch(void* const* d_in, const int* in_sizes, int n_in,
                              void* d_out, int out_size, void* d_ws,
                              size_t ws_size, hipStream_t stream) {
  const float* x = (const float*)d_in[0];
  const float* Wq = (const float*)d_in[1];
  const float* Wk = (const float*)d_in[2];
  const float* Wv = (const float*)d_in[3];
  const float* Wp = (const float*)d_in[4];
  const unsigned* mask = (const unsigned*)d_in[5];
  float* out = (float*)d_out;

  _Float16* Wh = (_Float16*)d_ws;                   // 0.5 MB
  _Float16* XT = Wh + 4 * 65536;                    // 12.6 MB n-major
  _Float16* qh = XT + (size_t)B_ * BHN;             // 12.6 MB n-major (scaled)
  _Float16* kh = qh + (size_t)B_ * BHN;             // 12.6 MB n-major
  _Float16* vh = kh + (size_t)B_ * BHN;             // 12.6 MB c-major
  _Float16* yT = vh + (size_t)B_ * BHN;             // 12.6 MB n-major
  unsigned long long* mb = (unsigned long long*)(yT + (size_t)B_ * BHN);

  mask_bits_kernel<<<1, 256, 0, stream>>>(mask, mb);
  convw_kernel<<<128, 256, 0, stream>>>(Wq, Wk, Wv, Wp, Wh);
  convxt_kernel<<<dim3(48, 4, B_), 256, 0, stream>>>(x, XT);

  dim3 g1(24, 2, B_ * 3);
  mgemm_kernel<0><<<g1, 256, 0, stream>>>(Wh, 0, XT, qh, kh, vh, nullptr, 3);

  attn_kernel<<<dim3(512), 256, 0, stream>>>(qh, kh, vh, mb, yT);

  dim3 g3(24, 2, B_);
  mgemm_kernel<1><<<g3, 256, 0, stream>>>(Wh, 3, yT, nullptr, nullptr, nullptr,
                                          out, 1);
}